// Round 3
// baseline (363.290 us; speedup 1.0000x reference)
//
#include <hip/hip_runtime.h>

#define NN 256
#define CC 64
#define TT 64
#define VV 25
#define SS 3
#define RR 8
#define OO 64
#define HH 16

typedef _Float16 f16;
typedef _Float16 f16x8 __attribute__((ext_vector_type(8)));
typedef float f32x4 __attribute__((ext_vector_type(4)));

#define IBN 0.9999950000374997f   /* 1/sqrt(1+1e-5) */

#define MG_NSTRIDE 153600         /* 3*64*25*32 f16 per n */

__device__ __forceinline__ float tanh_fast(float xx) {
  // tanh(x) = 1 - 2/(exp(2x)+1); exact at +-inf, ~1e-6 rel error
  float e = __expf(2.0f * xx);
  return 1.0f - __fdividef(2.0f, e + 1.0f);
}

// ---------------------------------------------------------------------------
// Kernel 1 (grid 256 = per n): fused preprocessing. One kernel, x read once.
//  - xm: per-thread CONTIGUOUS 400-float chunk (c, t-quarter), 4 batches of
//    25 f32x4 loads (bounded unroll -> bounded live range), LDS reduce
//  - x1/x2 (1x1 convs on xm), SE gate analytic (BN folded)
//  - per s: att = tanh_fast(x1[u]-x2[v]) in LDS, m-pass with register
//    softmax (thread owns (2 o, v) column), LDS transpose per 16-o quarter,
//    coalesced f16x8 stores of m_g [s][o][u:25][v pad 32] (pad zeroed once)
//  - block 0 packs w3 in MFMA A-frag order
// ---------------------------------------------------------------------------
__global__ __launch_bounds__(256) void k1(
    const float* __restrict__ x, const float* __restrict__ PA,
    const float* __restrict__ alpha,
    const float* __restrict__ w1, const float* __restrict__ b1,
    const float* __restrict__ w2, const float* __restrict__ b2,
    const float* __restrict__ w3, const float* __restrict__ b3,
    const float* __restrict__ w4, const float* __restrict__ b4,
    const float* __restrict__ bn_w, const float* __restrict__ bn_b,
    const float* __restrict__ se_w1, const float* __restrict__ se_b1,
    const float* __restrict__ se_w2, const float* __restrict__ se_b2,
    f16* __restrict__ m_g, float* __restrict__ se_g, f16* __restrict__ w3p_g)
{
  __shared__ float part[64][4][25];                           // 25,600 B
  __shared__ float xms[1600];                                 //  6,400 B
  __shared__ float x1s[600], x2s[600];                        //  4,800 B
  __shared__ float w1s[1536], w2s[1536];                      // 12,288 B
  __shared__ float asym_s[1875];                              //  7,500 B
  __shared__ __attribute__((aligned(16))) float att2[5000];   // 20,000 B [uv][r]
  __shared__ __attribute__((aligned(16))) f16 mt[16][25][32]; // 25,600 B
  __shared__ float xmv[64], pooledv[64], hbuf[16];

  int n = blockIdx.x, tid = threadIdx.x;

  for (int i = tid; i < 1536; i += 256) { w1s[i] = w1[i]; w2s[i] = w2[i]; }
  for (int i = tid; i < 1875; i += 256) {
    int s = i / 625, rem = i - s*625, u = rem / 25, v = rem - u*25;
    asym_s[i] = PA[s*625 + u*25 + v] + PA[s*625 + v*25 + u];
  }
  // zero mt v-pads (25..31) once; compute never touches them
  for (int i = tid; i < 2800; i += 256) {
    int o = i / 175, rem = i - o*175, u = rem / 7, k = rem - u*7;
    mt[o][u][25 + k] = (f16)0.f;
  }

  // ---- xm: contiguous chunk per thread, bounded unroll
  {
    int c = tid >> 2, tq = tid & 3;
    const float* p = x + (size_t)(n*64 + c)*1600 + tq*400;   // 16B aligned
    float acc[25];
    #pragma unroll
    for (int i = 0; i < 25; ++i) acc[i] = 0.f;
    for (int blk = 0; blk < 4; ++blk) {      // 100%25==0: phases repeat
      const float* pb = p + blk*100;
      #pragma unroll
      for (int j = 0; j < 25; ++j) {
        f32x4 vv = *(const f32x4*)(pb + 4*j);
        acc[(4*j + 0) % 25] += vv[0];
        acc[(4*j + 1) % 25] += vv[1];
        acc[(4*j + 2) % 25] += vv[2];
        acc[(4*j + 3) % 25] += vv[3];
      }
    }
    #pragma unroll
    for (int i = 0; i < 25; ++i) part[c][tq][i] = acc[i];
  }
  __syncthreads();

  for (int idx = tid; idx < 1600; idx += 256) {
    int cc = idx / 25, v = idx - cc*25;
    xms[idx] = (part[cc][0][v] + part[cc][1][v] + part[cc][2][v] + part[cc][3][v])
               * (1.0f/64.0f);
  }
  __syncthreads();

  // ---- x1/x2: [S*R, V]
  for (int idx = tid; idx < 600; idx += 256) {
    int sr = idx / 25, v = idx - sr*25;
    float a1 = b1[sr], a2 = b2[sr];
    #pragma unroll
    for (int c = 0; c < 64; ++c) {
      float xv = xms[c*25 + v];
      a1 += xv * w1s[sr*64 + c];
      a2 += xv * w2s[sr*64 + c];
    }
    x1s[idx] = a1; x2s[idx] = a2;
  }

  // ---- SE gate (softmax rows sum to 1 => pooled depends only on xm)
  if (tid < 64) {
    float s = 0.f;
    #pragma unroll
    for (int v = 0; v < 25; ++v) s += xms[tid*25 + v];
    xmv[tid] = s * (1.0f/25.0f);
  }
  __syncthreads();
  if (tid < 64) {
    int o = tid;
    float pp = b3[o] + b3[64 + o] + b3[128 + o];
    for (int cc = 0; cc < 64; ++cc)
      pp += xmv[cc] * (w3[o*64 + cc] + w3[4096 + o*64 + cc] + w3[8192 + o*64 + cc]);
    pooledv[o] = IBN * bn_w[o] * pp + bn_b[o];
  }
  __syncthreads();
  if (tid < 16) {
    float hh = se_b1[tid];
    for (int o = 0; o < 64; ++o) hh += pooledv[o] * se_w1[tid*64 + o];
    hbuf[tid] = fmaxf(hh, 0.0f);
  }
  __syncthreads();
  if (tid < 64) {
    float t = se_b2[tid];
    for (int j = 0; j < 16; ++j) t += hbuf[j] * se_w2[tid*16 + j];
    se_g[n*64 + tid] = 1.0f / (1.0f + __expf(-t));
  }

  // ---- per-subset: att -> m-pass -> softmax -> transpose -> coalesced store
  f16x8* mg8 = (f16x8*)(m_g + (size_t)n*MG_NSTRIDE);
  for (int s = 0; s < 3; ++s) {
    __syncthreads();                         // att2 reuse vs previous m-pass
    for (int idx = tid; idx < 5000; idx += 256) {
      int uv = idx >> 3, r = idx & 7;
      int u = uv / 25, v = uv - u*25;
      att2[idx] = tanh_fast(x1s[(s*8 + r)*25 + u] - x2s[(s*8 + r)*25 + v]);
    }
    __syncthreads();

    float alphav = alpha[s];
    for (int oq = 0; oq < 4; ++oq) {
      if (tid < 200) {
        int ot = tid / 25, v = tid - ot*25;
        int o0 = oq*16 + ot*2;
        float w4r[2][8], b4r[2];
        #pragma unroll
        for (int oo = 0; oo < 2; ++oo) {
          b4r[oo] = b4[s*64 + o0 + oo];
          #pragma unroll
          for (int r = 0; r < 8; ++r) w4r[oo][r] = w4[(s*64 + o0 + oo)*8 + r];
        }
        float acc[2][25];
        #pragma unroll
        for (int u = 0; u < 25; ++u) {
          const float* ap = &att2[(u*25 + v)*8];
          f32x4 a0 = *(const f32x4*)ap;
          f32x4 a1 = *(const f32x4*)(ap + 4);
          float asv = asym_s[s*625 + u*25 + v];
          #pragma unroll
          for (int oo = 0; oo < 2; ++oo) {
            float t = b4r[oo];
            t += a0[0]*w4r[oo][0] + a0[1]*w4r[oo][1] + a0[2]*w4r[oo][2] + a0[3]*w4r[oo][3];
            t += a1[0]*w4r[oo][4] + a1[1]*w4r[oo][5] + a1[2]*w4r[oo][6] + a1[3]*w4r[oo][7];
            acc[oo][u] = t*alphav + asv;
          }
        }
        #pragma unroll
        for (int oo = 0; oo < 2; ++oo) {
          float mx = -1e30f;
          #pragma unroll
          for (int u = 0; u < 25; ++u) mx = fmaxf(mx, acc[oo][u]);
          float sum = 0.f;
          #pragma unroll
          for (int u = 0; u < 25; ++u) {
            float e = __expf(acc[oo][u] - mx); acc[oo][u] = e; sum += e;
          }
          float inv = 1.0f / sum;
          #pragma unroll
          for (int u = 0; u < 25; ++u) mt[ot*2 + oo][u][v] = (f16)(acc[oo][u]*inv);
        }
      }
      __syncthreads();
      // coalesced 16B stores: m_g[s][o][u][v:32]
      for (int idx = tid; idx < 1600; idx += 256) {
        int ol = idx / 100, rem = idx - ol*100, u = rem >> 2, vc = rem & 3;
        int o = oq*16 + ol;
        mg8[((size_t)(s*64 + o)*25 + u)*4 + vc] = *(const f16x8*)&mt[ol][u][vc*8];
      }
      __syncthreads();
    }
  }

  if (n == 0) {
    // pack w3 into MFMA A-fragment order:
    // w3p[((mi*2+kk)*64+lane)*8+j] = w3[m=mi*16+(lane&15)][c=kk*32+(lane>>4)*8+j]
    for (int idx = tid; idx < 12288; idx += 256) {
      int j = idx & 7, lane = (idx >> 3) & 63, kk = (idx >> 9) & 1, mi = idx >> 10;
      int s = mi >> 2, o = ((mi & 3) << 4) + (lane & 15);
      int cc = kk*32 + ((lane >> 4) << 3) + j;
      w3p_g[idx] = (f16)w3[(s*64 + o)*64 + cc];
    }
  }
}

// ---------------------------------------------------------------------------
// Kernel C: UNCHANGED from round 2 (84.5 us measured). Per (n, t-tile of 16):
//  stage1: Z[16 so][16t x 25v] = W3 * X + b3         (16x16x32 f16 MFMA)
//  stage2: Y[t][u] += Z[t][v] * m[u][v]              (B-frags of m direct
//          from global, prefetched before the stage1 barrier)
//  epilogue: out = relu(Y*ibn*bn_w*se + bn_b*se + x)
// ---------------------------------------------------------------------------
struct __align__(16) SmemC {
  f16   xsT[400][72];      // X tile transposed [j=t*25+v][c], pad 72
  f16   zs[16][16][40];    // Z  [o'][t][v], row pad 40
  float b3s[192];
};                          // 78,848 B

__global__ __launch_bounds__(256, 2) void kc(
    const float* __restrict__ x, const float* __restrict__ b3,
    const float* __restrict__ bn_w, const float* __restrict__ bn_b,
    const f16* __restrict__ m_g, const float* __restrict__ se_g,
    const f16* __restrict__ w3p_g, float* __restrict__ out)
{
  __shared__ SmemC sm;
  int bid = blockIdx.x;
  int xcd = bid & 7, ii = bid >> 3;        // same-n tiles land on same XCD
  int n = xcd*32 + (ii >> 2), tt = ii & 3;
  int tid = threadIdx.x;
  int lane = tid & 63, w = tid >> 6, q = lane >> 4, l15 = lane & 15;

  {
    const float* xb = x + (size_t)n*CC*1600 + tt*400;
    #pragma unroll
    for (int it = 0; it < 50; ++it) {
      int idx = it*256 + tid;                 // < 12800 (c-pairs x j)
      int cp = idx / 400, j = idx - cp*400;
      float v0 = xb[(2*cp)*1600 + j];
      float v1 = xb[(2*cp + 1)*1600 + j];
      f16* p = &sm.xsT[j][2*cp];
      p[0] = (f16)v0; p[1] = (f16)v1;
    }
    if (tid < 192) sm.b3s[tid] = b3[tid];
    for (int i = tid; i < 3840; i += 256) {   // zs cols v=25..39 := 0
      int op = i / 240, rem = i - op*240, t = rem / 15, v = 25 + (rem - t*15);
      sm.zs[op][t][v] = (f16)0.f;
    }
  }
  __syncthreads();

  const f16x8* w3pv = (const f16x8*)w3p_g;
  const f16x8* mgv  = (const f16x8*)(m_g + (size_t)n*MG_NSTRIDE);

  for (int ob = 0; ob < 4; ++ob) {
    f32x4 yacc[4][2];
    #pragma unroll
    for (int i = 0; i < 4; ++i) {
      yacc[i][0] = (f32x4){0.f,0.f,0.f,0.f};
      yacc[i][1] = (f32x4){0.f,0.f,0.f,0.f};
    }

    for (int s = 0; s < 3; ++s) {
      // prefetch m B-frags (global/L2) + w3 A-frags; hidden under stage1
      f16x8 bm[4][2];
      int u2 = 16 + l15; if (u2 > 24) u2 = 24;   // clamp, cols discarded
      #pragma unroll
      for (int i = 0; i < 4; ++i) {
        int o = ob*16 + w*4 + i;
        int rb = (s*64 + o)*25;
        bm[i][0] = mgv[(rb + l15)*4 + q];        // m[u=l15][v=q*8..]
        bm[i][1] = mgv[(rb + u2)*4 + q];
      }
      int mi = s*4 + ob;
      f16x8 a0 = w3pv[(mi*2 + 0)*64 + lane];
      f16x8 a1 = w3pv[(mi*2 + 1)*64 + lane];

      __syncthreads();   // zs: previous stage2 reads done

      for (int ni = w; ni < 25; ni += 4) {
        int row = ni*16 + l15;                   // j = t*25+v (D n-col)
        f16x8 bf0 = *(const f16x8*)&sm.xsT[row][q*8];
        f16x8 bf1 = *(const f16x8*)&sm.xsT[row][32 + q*8];
        f32x4 acc = (f32x4){0.f,0.f,0.f,0.f};
        acc = __builtin_amdgcn_mfma_f32_16x16x32_f16(a0, bf0, acc, 0, 0, 0);
        acc = __builtin_amdgcn_mfma_f32_16x16x32_f16(a1, bf1, acc, 0, 0, 0);
        int t = row / 25, v = row - t*25;
        #pragma unroll
        for (int rg = 0; rg < 4; ++rg) {
          int op = q*4 + rg;                     // D m-row = o'
          sm.zs[op][t][v] = (f16)(acc[rg] + sm.b3s[s*64 + ob*16 + op]);
        }
      }
      __syncthreads();

      #pragma unroll
      for (int i = 0; i < 4; ++i) {
        int op = w*4 + i;
        f16x8 az = *(const f16x8*)&sm.zs[op][l15][q*8];   // A[t][v]
        yacc[i][0] = __builtin_amdgcn_mfma_f32_16x16x32_f16(az, bm[i][0], yacc[i][0], 0, 0, 0);
        yacc[i][1] = __builtin_amdgcn_mfma_f32_16x16x32_f16(az, bm[i][1], yacc[i][1], 0, 0, 0);
      }
    }

    #pragma unroll
    for (int i = 0; i < 4; ++i) {
      int op = w*4 + i, o = ob*16 + op;
      float sev   = se_g[n*64 + o];
      float scale = IBN * bn_w[o] * sev;
      float bias  = bn_b[o] * sev;
      #pragma unroll
      for (int ut = 0; ut < 2; ++ut) {
        int u = ut*16 + l15;
        if (u < 25) {
          #pragma unroll
          for (int rg = 0; rg < 4; ++rg) {
            int t = q*4 + rg;                               // D m-row = t
            float xres = (float)sm.xsT[t*25 + u][o];
            float val = yacc[i][ut][rg]*scale + bias + xres;
            out[(((size_t)n*64 + o)*64 + tt*16 + t)*25 + u] = fmaxf(val, 0.0f);
          }
        }
      }
    }
  }
}

// ---------------------------------------------------------------------------
extern "C" void kernel_launch(void* const* d_in, const int* in_sizes, int n_in,
                              void* d_out, int out_size, void* d_ws, size_t ws_size,
                              hipStream_t stream)
{
  const float* x    = (const float*)d_in[0];
  const float* PA   = (const float*)d_in[1];
  const float* alp  = (const float*)d_in[2];
  const float* w1   = (const float*)d_in[3];
  const float* b1   = (const float*)d_in[4];
  const float* w2   = (const float*)d_in[5];
  const float* b2   = (const float*)d_in[6];
  const float* w3   = (const float*)d_in[7];
  const float* b3   = (const float*)d_in[8];
  const float* w4   = (const float*)d_in[9];
  const float* b4   = (const float*)d_in[10];
  const float* bnw  = (const float*)d_in[11];
  const float* bnb  = (const float*)d_in[12];
  const float* sw1  = (const float*)d_in[13];
  const float* sb1  = (const float*)d_in[14];
  const float* sw2  = (const float*)d_in[15];
  const float* sb2  = (const float*)d_in[16];

  char* ws = (char*)d_ws;
  f16*   m_g   = (f16*)ws;                          // 78,643,200 B
  float* se_g  = (float*)(ws + 78643200);           // 65,536 B
  f16*   w3p_g = (f16*)(ws + 78643200 + 65536);     // 24,576 B

  float* out = (float*)d_out;

  k1<<<256, 256, 0, stream>>>(x, PA, alp, w1, b1, w2, b2, w3, b3, w4, b4,
                              bnw, bnb, sw1, sb1, sw2, sb2, m_g, se_g, w3p_g);
  kc<<<1024, 256, 0, stream>>>(x, b3, bnw, bnb, m_g, se_g, w3p_g, out);
}

// Round 4
// 327.563 us; speedup vs baseline: 1.1091x; 1.1091x over previous
//
#include <hip/hip_runtime.h>

#define NN 256
#define CC 64
#define TT 64
#define VV 25
#define SS 3
#define RR 8
#define OO 64
#define HH 16

typedef _Float16 f16;
typedef _Float16 f16x8 __attribute__((ext_vector_type(8)));
typedef float f32x4 __attribute__((ext_vector_type(4)));

#define IBN 0.9999950000374997f   /* 1/sqrt(1+1e-5) */

#define MG_NSTRIDE 153600         /* 3*64*25*32 f16 per n */

__device__ __forceinline__ float tanh_fast(float xx) {
  // tanh(x) = 1 - 2/(exp(2x)+1); exact at +-inf, ~1e-6 rel error
  float e = __expf(2.0f * xx);
  return 1.0f - __fdividef(2.0f, e + 1.0f);
}

// mt swizzle: f16 index XOR, 8-f16 (16B) granular -> b128 reads stay aligned.
// spreads the o-index into bank bits (o alone contributes 0 mod 32 words).
__device__ __forceinline__ int mti(int mo, int u, int v) {
  return (mo*800 + u*32 + v) ^ ((mo & 6) << 2);
}

// ---------------------------------------------------------------------------
// Kernel 1 (grid 256 = per n, 512 threads = 8 waves/CU): fused preprocessing.
//  - xm: per-thread CONTIGUOUS 200-float chunk, LDS reduce
//  - x1/x2, SE gate analytic (BN folded)
//  - per s: att=tanh_fast in LDS; m-pass 32-o phases (400 active threads),
//    register softmax; swizzled mt; coalesced f16x8 m_g stores
//  - block 0 packs w3 in MFMA A-frag order
// ---------------------------------------------------------------------------
__global__ __launch_bounds__(512) void k1(
    const float* __restrict__ x, const float* __restrict__ PA,
    const float* __restrict__ alpha,
    const float* __restrict__ w1, const float* __restrict__ b1,
    const float* __restrict__ w2, const float* __restrict__ b2,
    const float* __restrict__ w3, const float* __restrict__ b3,
    const float* __restrict__ w4, const float* __restrict__ b4,
    const float* __restrict__ bn_w, const float* __restrict__ bn_b,
    const float* __restrict__ se_w1, const float* __restrict__ se_b1,
    const float* __restrict__ se_w2, const float* __restrict__ se_b2,
    f16* __restrict__ m_g, float* __restrict__ se_g, f16* __restrict__ w3p_g)
{
  __shared__ float part[64][8][25];                           // 51,200 B
  __shared__ float xms[1600];                                 //  6,400 B
  __shared__ float x1s[600], x2s[600];                        //  4,800 B
  __shared__ float w1s[1536], w2s[1536];                      // 12,288 B
  __shared__ float asym_s[1875];                              //  7,500 B
  __shared__ __attribute__((aligned(16))) float att2[5000];   // 20,000 B [uv][r]
  __shared__ __attribute__((aligned(16))) f16 mtf[25600];     // 51,200 B [32 o]
  __shared__ float xmv[64], pooledv[64], hbuf[16];
  // total ~153.9 KB -> 1 block/CU, 8 waves

  int n = blockIdx.x, tid = threadIdx.x;

  for (int i = tid; i < 1536; i += 512) { w1s[i] = w1[i]; w2s[i] = w2[i]; }
  for (int i = tid; i < 1875; i += 512) {
    int s = i / 625, rem = i - s*625, u = rem / 25, v = rem - u*25;
    asym_s[i] = PA[s*625 + u*25 + v] + PA[s*625 + v*25 + u];
  }
  // zero mt v-pads (25..31) once (swizzled slots; never overwritten)
  for (int i = tid; i < 5600; i += 512) {
    int mo = i / 175, rem = i - mo*175, u = rem / 7, v = 25 + (rem - u*7);
    mtf[mti(mo, u, v)] = (f16)0.f;
  }

  // ---- xm: contiguous 200-float chunk per thread
  {
    int c = tid >> 3, tq = tid & 7;
    const float* p = x + (size_t)(n*64 + c)*1600 + tq*200;   // 16B aligned
    float acc[25];
    #pragma unroll
    for (int i = 0; i < 25; ++i) acc[i] = 0.f;
    for (int blk = 0; blk < 2; ++blk) {      // 100 floats per blk, 100%25==0
      const float* pb = p + blk*100;
      #pragma unroll
      for (int j = 0; j < 25; ++j) {
        f32x4 vv = *(const f32x4*)(pb + 4*j);
        acc[(4*j + 0) % 25] += vv[0];
        acc[(4*j + 1) % 25] += vv[1];
        acc[(4*j + 2) % 25] += vv[2];
        acc[(4*j + 3) % 25] += vv[3];
      }
    }
    #pragma unroll
    for (int i = 0; i < 25; ++i) part[c][tq][i] = acc[i];
  }
  __syncthreads();

  for (int idx = tid; idx < 1600; idx += 512) {
    int cc = idx / 25, v = idx - cc*25;
    float s = 0.f;
    #pragma unroll
    for (int tq = 0; tq < 8; ++tq) s += part[cc][tq][v];
    xms[idx] = s * (1.0f/64.0f);
  }
  __syncthreads();

  // ---- x1/x2: [S*R, V]
  for (int idx = tid; idx < 600; idx += 512) {
    int sr = idx / 25, v = idx - sr*25;
    float a1 = b1[sr], a2 = b2[sr];
    #pragma unroll
    for (int c = 0; c < 64; ++c) {
      float xv = xms[c*25 + v];
      a1 += xv * w1s[sr*64 + c];
      a2 += xv * w2s[sr*64 + c];
    }
    x1s[idx] = a1; x2s[idx] = a2;
  }

  // ---- SE gate (softmax rows sum to 1 => pooled depends only on xm)
  if (tid < 64) {
    float s = 0.f;
    #pragma unroll
    for (int v = 0; v < 25; ++v) s += xms[tid*25 + v];
    xmv[tid] = s * (1.0f/25.0f);
  }
  __syncthreads();
  if (tid < 64) {
    int o = tid;
    float pp = b3[o] + b3[64 + o] + b3[128 + o];
    for (int cc = 0; cc < 64; ++cc)
      pp += xmv[cc] * (w3[o*64 + cc] + w3[4096 + o*64 + cc] + w3[8192 + o*64 + cc]);
    pooledv[o] = IBN * bn_w[o] * pp + bn_b[o];
  }
  __syncthreads();
  if (tid < 16) {
    float hh = se_b1[tid];
    for (int o = 0; o < 64; ++o) hh += pooledv[o] * se_w1[tid*64 + o];
    hbuf[tid] = fmaxf(hh, 0.0f);
  }
  __syncthreads();
  if (tid < 64) {
    float t = se_b2[tid];
    for (int j = 0; j < 16; ++j) t += hbuf[j] * se_w2[tid*16 + j];
    se_g[n*64 + tid] = 1.0f / (1.0f + __expf(-t));
  }

  // ---- per-subset: att -> m-pass (2 phases x 32 o) -> swizzled mt ->
  //      coalesced f16x8 m_g stores
  f16x8* mg8 = (f16x8*)(m_g + (size_t)n*MG_NSTRIDE);
  for (int s = 0; s < 3; ++s) {
    __syncthreads();                         // att2/mt reuse vs prev phase
    for (int idx = tid; idx < 5000; idx += 512) {
      int uv = idx >> 3, r = idx & 7;
      int u = uv / 25, v = uv - u*25;
      att2[idx] = tanh_fast(x1s[(s*8 + r)*25 + u] - x2s[(s*8 + r)*25 + v]);
    }
    __syncthreads();

    float alphav = alpha[s];
    for (int oh = 0; oh < 2; ++oh) {
      if (tid < 400) {
        int ot = tid / 25, v = tid - ot*25;       // ot 0..15
        int o0 = oh*32 + ot*2;
        float w4r[2][8], b4r[2];
        #pragma unroll
        for (int oo = 0; oo < 2; ++oo) {
          b4r[oo] = b4[s*64 + o0 + oo];
          #pragma unroll
          for (int r = 0; r < 8; ++r) w4r[oo][r] = w4[(s*64 + o0 + oo)*8 + r];
        }
        float acc[2][25];
        #pragma unroll
        for (int u = 0; u < 25; ++u) {
          const float* ap = &att2[(u*25 + v)*8];
          f32x4 a0 = *(const f32x4*)ap;
          f32x4 a1 = *(const f32x4*)(ap + 4);
          float asv = asym_s[s*625 + u*25 + v];
          #pragma unroll
          for (int oo = 0; oo < 2; ++oo) {
            float t = b4r[oo];
            t += a0[0]*w4r[oo][0] + a0[1]*w4r[oo][1] + a0[2]*w4r[oo][2] + a0[3]*w4r[oo][3];
            t += a1[0]*w4r[oo][4] + a1[1]*w4r[oo][5] + a1[2]*w4r[oo][6] + a1[3]*w4r[oo][7];
            acc[oo][u] = t*alphav + asv;
          }
        }
        #pragma unroll
        for (int oo = 0; oo < 2; ++oo) {
          int mo = ot*2 + oo;
          float mx = -1e30f;
          #pragma unroll
          for (int u = 0; u < 25; ++u) mx = fmaxf(mx, acc[oo][u]);
          float sum = 0.f;
          #pragma unroll
          for (int u = 0; u < 25; ++u) {
            float e = __expf(acc[oo][u] - mx); acc[oo][u] = e; sum += e;
          }
          float inv = 1.0f / sum;
          #pragma unroll
          for (int u = 0; u < 25; ++u) mtf[mti(mo, u, v)] = (f16)(acc[oo][u]*inv);
        }
      }
      __syncthreads();
      // coalesced 16B stores: m_g[s][o][u][v:32]
      for (int idx = tid; idx < 3200; idx += 512) {
        int mo = idx / 100, rem = idx - mo*100, u = rem >> 2, vc = rem & 3;
        int o = oh*32 + mo;
        f16x8 val = *(const f16x8*)&mtf[mti(mo, u, vc*8)];
        mg8[((size_t)(s*64 + o)*25 + u)*4 + vc] = val;
      }
      __syncthreads();
    }
  }

  if (n == 0) {
    // pack w3 into MFMA A-fragment order:
    // w3p[((mi*2+kk)*64+lane)*8+j] = w3[m=mi*16+(lane&15)][c=kk*32+(lane>>4)*8+j]
    for (int idx = tid; idx < 12288; idx += 512) {
      int j = idx & 7, lane = (idx >> 3) & 63, kk = (idx >> 9) & 1, mi = idx >> 10;
      int s = mi >> 2, o = ((mi & 3) << 4) + (lane & 15);
      int cc = kk*32 + ((lane >> 4) << 3) + j;
      w3p_g[idx] = (f16)w3[(s*64 + o)*64 + cc];
    }
  }
}

// ---------------------------------------------------------------------------
// Kernel C (grid 512 = [n x t-half], 512 threads, 2 blocks/CU = 16 waves):
//  per t-tile (2 per block, xsT restaged between):
//  stage1: Z[16 so][16t x 25v] = W3 * X + b3         (16x16x32 f16 MFMA)
//  stage2: Y[t][u] += Z[t][v] * m[u][v]              (B-frags of m from
//          global, prefetched before the stage1 barrier)
//  epilogue: out = relu(Y*ibn*bn_w*se + bn_b*se + x)
//  xsT staging via b128 LDS writes (conflict-free) from 8 coalesced loads.
// ---------------------------------------------------------------------------
struct __align__(16) SmemC {
  f16   xsT[400][72];      // X tile transposed [j=t*25+v][c], pad 72
  f16   zs[16][16][40];    // Z  [o'][t][v], row pad 40
  float b3s[192];
};                          // 78,848 B -> x2 = 157.7 KB <= 160 KB

__global__ __launch_bounds__(512, 4) void kc(
    const float* __restrict__ x, const float* __restrict__ b3,
    const float* __restrict__ bn_w, const float* __restrict__ bn_b,
    const f16* __restrict__ m_g, const float* __restrict__ se_g,
    const f16* __restrict__ w3p_g, float* __restrict__ out)
{
  __shared__ SmemC sm;
  int bid = blockIdx.x;
  int xcd = bid & 7, ii = bid >> 3;        // same-n blocks land on same XCD
  int n = xcd*32 + (ii >> 1), th = ii & 1;
  int tid = threadIdx.x;
  int lane = tid & 63, w = tid >> 6, q = lane >> 4, l15 = lane & 15;

  if (tid < 192) sm.b3s[tid] = b3[tid];
  for (int i = tid; i < 3840; i += 512) {   // zs cols v=25..39 := 0 (K-pad)
    int op = i / 240, rem = i - op*240, t = rem / 15, v = 25 + (rem - t*15);
    sm.zs[op][t][v] = (f16)0.f;
  }

  const f16x8* w3pv = (const f16x8*)w3p_g;
  const f16x8* mgv  = (const f16x8*)(m_g + (size_t)n*MG_NSTRIDE);

  for (int tloc = 0; tloc < 2; ++tloc) {
    int tt = th*2 + tloc;
    __syncthreads();     // prev epilogue xsT residual reads done

    // ---- stage X tile: [cb:8][j:400] units, 8 coalesced scalar loads ->
    //      one b128 LDS write (start banks 4j+4cb, balanced -> conflict-free)
    {
      const float* xb = x + (size_t)n*CC*1600 + tt*400;
      for (int idx = tid; idx < 3200; idx += 512) {
        int cb = idx / 400, j = idx - cb*400;
        f16x8 hv;
        #pragma unroll
        for (int k = 0; k < 8; ++k) hv[k] = (f16)xb[(cb*8 + k)*1600 + j];
        *(f16x8*)&sm.xsT[j][cb*8] = hv;
      }
    }
    __syncthreads();

    for (int ob = 0; ob < 4; ++ob) {
      f32x4 yacc[2][2];
      #pragma unroll
      for (int i = 0; i < 2; ++i) {
        yacc[i][0] = (f32x4){0.f,0.f,0.f,0.f};
        yacc[i][1] = (f32x4){0.f,0.f,0.f,0.f};
      }

      for (int s = 0; s < 3; ++s) {
        // prefetch m B-frags (global/L2) + w3 A-frags; hidden under stage1
        f16x8 bm[2][2];
        int u2 = 16 + l15; if (u2 > 24) u2 = 24;   // clamp, cols discarded
        #pragma unroll
        for (int i = 0; i < 2; ++i) {
          int o = ob*16 + w*2 + i;
          int rb = (s*64 + o)*25;
          bm[i][0] = mgv[(rb + l15)*4 + q];        // m[u=l15][v=q*8..]
          bm[i][1] = mgv[(rb + u2)*4 + q];
        }
        int mi = s*4 + ob;
        f16x8 a0 = w3pv[(mi*2 + 0)*64 + lane];
        f16x8 a1 = w3pv[(mi*2 + 1)*64 + lane];

        __syncthreads();   // zs: previous stage2 reads done

        // ---- stage1: Z = W3*X + b3 -> zs (8 waves stride rows)
        for (int ni = w; ni < 25; ni += 8) {
          int row = ni*16 + l15;                   // j = t*25+v (D n-col)
          f16x8 bf0 = *(const f16x8*)&sm.xsT[row][q*8];
          f16x8 bf1 = *(const f16x8*)&sm.xsT[row][32 + q*8];
          f32x4 acc = (f32x4){0.f,0.f,0.f,0.f};
          acc = __builtin_amdgcn_mfma_f32_16x16x32_f16(a0, bf0, acc, 0, 0, 0);
          acc = __builtin_amdgcn_mfma_f32_16x16x32_f16(a1, bf1, acc, 0, 0, 0);
          int t = row / 25, v = row - t*25;
          #pragma unroll
          for (int rg = 0; rg < 4; ++rg) {
            int op = q*4 + rg;                     // D m-row = o'
            sm.zs[op][t][v] = (f16)(acc[rg] + sm.b3s[s*64 + ob*16 + op]);
          }
        }
        __syncthreads();

        // ---- stage2: Y[t][u] += Z[t][v] * m[u][v]
        #pragma unroll
        for (int i = 0; i < 2; ++i) {
          int op = w*2 + i;
          f16x8 az = *(const f16x8*)&sm.zs[op][l15][q*8];   // A[t][v]
          yacc[i][0] = __builtin_amdgcn_mfma_f32_16x16x32_f16(az, bm[i][0], yacc[i][0], 0, 0, 0);
          yacc[i][1] = __builtin_amdgcn_mfma_f32_16x16x32_f16(az, bm[i][1], yacc[i][1], 0, 0, 0);
        }
      }

      // ---- epilogue for this o-block: BN+SE+residual+ReLU
      #pragma unroll
      for (int i = 0; i < 2; ++i) {
        int op = w*2 + i, o = ob*16 + op;
        float sev   = se_g[n*64 + o];
        float scale = IBN * bn_w[o] * sev;
        float bias  = bn_b[o] * sev;
        #pragma unroll
        for (int ut = 0; ut < 2; ++ut) {
          int u = ut*16 + l15;
          if (u < 25) {
            #pragma unroll
            for (int rg = 0; rg < 4; ++rg) {
              int t = q*4 + rg;                               // D m-row = t
              float xres = (float)sm.xsT[t*25 + u][o];
              float val = yacc[i][ut][rg]*scale + bias + xres;
              out[(((size_t)n*64 + o)*64 + tt*16 + t)*25 + u] = fmaxf(val, 0.0f);
            }
          }
        }
      }
    }
  }
}

// ---------------------------------------------------------------------------
extern "C" void kernel_launch(void* const* d_in, const int* in_sizes, int n_in,
                              void* d_out, int out_size, void* d_ws, size_t ws_size,
                              hipStream_t stream)
{
  const float* x    = (const float*)d_in[0];
  const float* PA   = (const float*)d_in[1];
  const float* alp  = (const float*)d_in[2];
  const float* w1   = (const float*)d_in[3];
  const float* b1   = (const float*)d_in[4];
  const float* w2   = (const float*)d_in[5];
  const float* b2   = (const float*)d_in[6];
  const float* w3   = (const float*)d_in[7];
  const float* b3   = (const float*)d_in[8];
  const float* w4   = (const float*)d_in[9];
  const float* b4   = (const float*)d_in[10];
  const float* bnw  = (const float*)d_in[11];
  const float* bnb  = (const float*)d_in[12];
  const float* sw1  = (const float*)d_in[13];
  const float* sb1  = (const float*)d_in[14];
  const float* sw2  = (const float*)d_in[15];
  const float* sb2  = (const float*)d_in[16];

  char* ws = (char*)d_ws;
  f16*   m_g   = (f16*)ws;                          // 78,643,200 B
  float* se_g  = (float*)(ws + 78643200);           // 65,536 B
  f16*   w3p_g = (f16*)(ws + 78643200 + 65536);     // 24,576 B

  float* out = (float*)d_out;

  k1<<<256, 512, 0, stream>>>(x, PA, alp, w1, b1, w2, b2, w3, b3, w4, b4,
                              bnw, bnb, sw1, sb1, sw2, sb2, m_g, se_g, w3p_g);
  kc<<<512, 512, 0, stream>>>(x, b3, bnw, bnb, m_g, se_g, w3p_g, out);
}